// Round 4
// baseline (270.258 us; speedup 1.0000x reference)
//
#include <hip/hip_runtime.h>
#include <stdint.h>

#define T_DIM 2048
#define V_DIM 1024
#define B_DIM 8
#define NT 16            // T_DIM/128

typedef unsigned int u32;
typedef unsigned short u16;
typedef __attribute__((ext_vector_type(8))) short s16x8;
typedef __attribute__((ext_vector_type(4))) float f32x4;

__device__ __forceinline__ u16 f2bf(float x) {
  u32 u = __builtin_bit_cast(u32, x);
  u = u + 0x7FFFu + ((u >> 16) & 1u);   // round-to-nearest-even
  return (u16)(u >> 16);
}

// async global->LDS, 16B per lane (m97 pattern)
#define GLD16(gp, lp) __builtin_amdgcn_global_load_lds( \
    (const __attribute__((address_space(1))) u32*)(gp), \
    (__attribute__((address_space(3))) u32*)(lp), 16, 0, 0)

// ---------------------------------------------------------------------------
// C[m,n] = sum_k A[m,k] * Bt[n,k]   (bf16 row-major, fp32 accum)
// 128x256 tile, BK=32, 256 threads = 4 waves (2x2), each wave 64m x 128n.
// LDS XOR-swizzle (slot c of row r holds global chunk (c-(r>>1))&3) keeps
// ds_read_b128 fragment reads 2-way (free) instead of 8-way.
// MODE 0: plain; grid (N/256, M/128, nz).
// MODE 1: tril(A) output, T x T — grid (nb, 72); tiles bn<=bm>>1 only,
//         decoded bn-DESC/bm-DESC (heavy-first);
//         kmax=min((bm+1)*128,(bn+1)*256); epilogue masks gc>gr.
// MODE 2: causal-K — grid (N/256, nb, 16); bm=15-z (heavy-first),
//         kmax=(bm+1)*128 (left operand is tril).
// F32OUT: write float + bias, else bf16.
// ---------------------------------------------------------------------------
template<int MODE, bool F32OUT>
__global__ void __launch_bounds__(256, 2)
gemm_bt(const u16* __restrict__ A, int lda, long long batchA,
        const u16* __restrict__ Bt, int ldb, long long batchB,
        void* __restrict__ Cv, int ldc, long long batchC,
        int K, float bias)
{
  int bn, bm, bz;
  if (MODE == 0) {
    bn = blockIdx.x; bm = blockIdx.y; bz = blockIdx.z;
  } else if (MODE == 1) {
    bz = blockIdx.x;
    int tau = blockIdx.y;            // 0..71, bn desc then bm desc
    int b = 7, off = 0;
    while (tau >= off + (16 - 2 * b)) { off += 16 - 2 * b; b--; }
    bn = b; bm = 15 - (tau - off);
  } else {                           // MODE 2
    bn = blockIdx.x; bz = blockIdx.y; bm = (NT - 1) - blockIdx.z;
  }
  const u16* Ab = A + (long long)bz * batchA;
  const u16* Bb = Bt + (long long)bz * batchB;
  int m0 = bm * 128, n0 = bn * 256;
  int kmax = K;
  if (MODE == 1) {
    int kl1 = (bm + 1) * 128, kl2 = (bn + 1) * 256;
    int kl = kl1 < kl2 ? kl1 : kl2;
    kmax = kl < K ? kl : K;
  }
  if (MODE == 2) { int kl = (bm + 1) * 128; kmax = kl < K ? kl : K; }

  __shared__ u16 As[128 * 32];   // 8 KB
  __shared__ u16 Bs[256 * 32];   // 16 KB

  int tid = threadIdx.x;
  int lane = tid & 63;
  int wid = tid >> 6;
  int wm = wid >> 1, wn = wid & 1;

  f32x4 acc[4][8] = {};

  // staging: thread t covers row r=t>>2 (+64/128/192), LDS slot t&3.
  // Global chunk in slot c is (c - (r>>1))&3; +64k rows keep same cg (mod 4).
  int r = tid >> 2;
  int cslot = tid & 3;
  int cg = ((cslot - (r >> 1)) & 3) * 8;
  const u16* ga0 = Ab + (long long)(m0 + r) * lda + cg;
  const u16* ga1 = ga0 + (long long)64 * lda;
  const u16* gb0 = Bb + (long long)(n0 + r) * ldb + cg;
  const u16* gb1 = gb0 + (long long)64 * ldb;
  const u16* gb2 = gb0 + (long long)128 * ldb;
  const u16* gb3 = gb0 + (long long)192 * ldb;
  u16* la0 = As + r * 32 + cslot * 8;   // byte offset = tid*16 (wave-contig)
  u16* la1 = la0 + 64 * 32;
  u16* lb0 = Bs + r * 32 + cslot * 8;
  u16* lb1 = lb0 + 64 * 32;
  u16* lb2 = lb0 + 128 * 32;
  u16* lb3 = lb0 + 192 * 32;

  int rm = lane & 15;
  int q8 = (((lane >> 4) + (rm >> 1)) & 3) * 8;   // physical chunk to read

  for (int k0 = 0; k0 < kmax; k0 += 32) {
    GLD16(ga0 + k0, la0);
    GLD16(ga1 + k0, la1);
    GLD16(gb0 + k0, lb0);
    GLD16(gb1 + k0, lb1);
    GLD16(gb2 + k0, lb2);
    GLD16(gb3 + k0, lb3);
    __syncthreads();
    s16x8 af[4], bfv[8];
#pragma unroll
    for (int mi = 0; mi < 4; mi++)
      af[mi] = *(const s16x8*)&As[(wm * 64 + mi * 16 + rm) * 32 + q8];
#pragma unroll
    for (int ni = 0; ni < 8; ni++)
      bfv[ni] = *(const s16x8*)&Bs[(wn * 128 + ni * 16 + rm) * 32 + q8];
#pragma unroll
    for (int mi = 0; mi < 4; mi++)
#pragma unroll
      for (int ni = 0; ni < 8; ni++)
        acc[mi][ni] = __builtin_amdgcn_mfma_f32_16x16x32_bf16(
            af[mi], bfv[ni], acc[mi][ni], 0, 0, 0);
    __syncthreads();
  }

  // C/D layout (m89-verified): col = lane&15, row = (lane>>4)*4 + reg
  int col = lane & 15;
  int rq = (lane >> 4) * 4;
#pragma unroll
  for (int mi = 0; mi < 4; mi++) {
#pragma unroll
    for (int ni = 0; ni < 8; ni++) {
      int lr = wm * 64 + mi * 16 + rq;          // local row (base of 4)
      int lc = wn * 128 + ni * 16 + col;        // local col
#pragma unroll
      for (int rr = 0; rr < 4; rr++) {
        float val = acc[mi][ni][rr];
        if (MODE == 1 && (n0 + lc) > (m0 + lr + rr)) val = 0.f;  // causal
        long long off = (long long)(m0 + lr + rr) * ldc + (n0 + lc);
        if (F32OUT) {
          float* C = (float*)Cv + (long long)bz * batchC;
          C[off] = val + bias;
        } else {
          u16* C = (u16*)Cv + (long long)bz * batchC;
          C[off] = f2bf(val);
        }
      }
    }
  }
}

// ---------------------------------------------------------------------------
// transpose + cast two VxV fp32 matrices -> bf16 (dst[i][o] = src[o][i])
// ---------------------------------------------------------------------------
__global__ void transpose_cast2(const float* __restrict__ s0, u16* __restrict__ d0,
                                const float* __restrict__ s1, u16* __restrict__ d1)
{
  const float* src = blockIdx.z ? s1 : s0;
  u16* dst = blockIdx.z ? d1 : d0;
  __shared__ float tile[32][33];
  int x0 = blockIdx.x * 32, y0 = blockIdx.y * 32;
  int tx = threadIdx.x, ty = threadIdx.y;
#pragma unroll
  for (int k = 0; k < 4; k++)
    tile[ty + k * 8][tx] = src[(long long)(y0 + ty + k * 8) * V_DIM + x0 + tx];
  __syncthreads();
#pragma unroll
  for (int k = 0; k < 4; k++)
    dst[(long long)(x0 + ty + k * 8) * V_DIM + y0 + tx] = f2bf(tile[tx][ty + k * 8]);
}

__global__ void cast_bf16(const float* __restrict__ src, u16* __restrict__ dst)
{
  int i = blockIdx.x * 1024 + threadIdx.x;
#pragma unroll
  for (int k = 0; k < 4; k++) dst[i + k * 256] = f2bf(src[i + k * 256]);
}

// P[s][u] = v[s-u] for u<=s else 0  (T x T bf16), 16B stores
__global__ void build_p(const float* __restrict__ v, u16* __restrict__ P)
{
  int gid = blockIdx.x * 256 + threadIdx.x;
  int e0 = gid * 8;
  int s = e0 >> 11, u0 = e0 & 2047;
  s16x8 o;
#pragma unroll
  for (int k = 0; k < 8; k++) {
    int u = u0 + k;
    o[k] = (short)((u <= s) ? f2bf(v[s - u]) : (u16)0);
  }
  *(s16x8*)&P[e0] = o;
}

// G[z][t][u] = M[idx[b,t]][idx[b,u]] — one block per (t,z), 16B stores
__global__ void __launch_bounds__(256)
gather_g(const int* __restrict__ idx, const u16* __restrict__ Mb,
         u16* __restrict__ G, int b0)
{
  int t = blockIdx.x, z = blockIdx.y;
  const int* idxrow = idx + (long long)(b0 + z) * T_DIM;
  __shared__ u16 Mrow[V_DIM];
  int tid = threadIdx.x;
  int rowid = idxrow[t];
  const u32* src = (const u32*)(Mb + (long long)rowid * V_DIM);
  u32* dstl = (u32*)Mrow;
  dstl[tid] = src[tid];
  dstl[tid + 256] = src[tid + 256];
  __syncthreads();
  int u0 = tid * 8;
  int4 i0 = *(const int4*)&idxrow[u0];
  int4 i1 = *(const int4*)&idxrow[u0 + 4];
  s16x8 o;
  o[0] = (short)Mrow[i0.x]; o[1] = (short)Mrow[i0.y];
  o[2] = (short)Mrow[i0.z]; o[3] = (short)Mrow[i0.w];
  o[4] = (short)Mrow[i1.x]; o[5] = (short)Mrow[i1.y];
  o[6] = (short)Mrow[i1.z]; o[7] = (short)Mrow[i1.w];
  *(s16x8*)&G[((long long)z * T_DIM + t) * T_DIM + u0] = o;
}

// Yt[z][j][s] = Wv[j][idx[b,s]] — one block per (j,z), 16B stores
__global__ void __launch_bounds__(256)
gather_y(const int* __restrict__ idx, const u16* __restrict__ Wvb,
         u16* __restrict__ Yt, int b0)
{
  int j = blockIdx.x, z = blockIdx.y;
  const int* idxrow = idx + (long long)(b0 + z) * T_DIM;
  __shared__ u16 Wrow[V_DIM];
  int tid = threadIdx.x;
  const u32* src = (const u32*)(Wvb + (long long)j * V_DIM);
  u32* dstl = (u32*)Wrow;
  dstl[tid] = src[tid];
  dstl[tid + 256] = src[tid + 256];
  __syncthreads();
  int s0 = tid * 8;
  int4 i0 = *(const int4*)&idxrow[s0];
  int4 i1 = *(const int4*)&idxrow[s0 + 4];
  s16x8 o;
  o[0] = (short)Wrow[i0.x]; o[1] = (short)Wrow[i0.y];
  o[2] = (short)Wrow[i0.z]; o[3] = (short)Wrow[i0.w];
  o[4] = (short)Wrow[i1.x]; o[5] = (short)Wrow[i1.y];
  o[6] = (short)Wrow[i1.z]; o[7] = (short)Wrow[i1.w];
  *(s16x8*)&Yt[((long long)z * V_DIM + j) * T_DIM + s0] = o;
}

// ---------------------------------------------------------------------------
extern "C" void kernel_launch(void* const* d_in, const int* in_sizes, int n_in,
                              void* d_out, int out_size, void* d_ws, size_t ws_size,
                              hipStream_t stream)
{
  const int*   idx = (const int*)d_in[0];
  const float* v   = (const float*)d_in[1];
  const float* Wk  = (const float*)d_in[2];
  const float* Wq  = (const float*)d_in[3];
  const float* Wv  = (const float*)d_in[4];
  float* out = (float*)d_out;

  char* p = (char*)d_ws;
  const size_t SZ_VV = (size_t)V_DIM * V_DIM * 2;   // 2 MB bf16
  const size_t SZ_TT = (size_t)T_DIM * T_DIM * 2;   // 8 MB bf16
  const size_t SZ_VT = (size_t)V_DIM * T_DIM * 2;   // 4 MB bf16
  u16* WqT = (u16*)p; p += SZ_VV;
  u16* WkT = (u16*)p; p += SZ_VV;
  u16* Wvb = (u16*)p; p += SZ_VV;
  u16* Mb  = (u16*)p; p += SZ_VV;
  u16* P   = (u16*)p; p += SZ_TT;
  size_t used = (size_t)(p - (char*)d_ws);
  size_t per = 2 * SZ_TT + SZ_VT;                    // G + A + Yt per batch
  int nb = 8;
  while (nb > 1 && used + (size_t)nb * per > ws_size) nb >>= 1;
  u16* G    = (u16*)p; p += (size_t)nb * SZ_TT;
  u16* Abuf = (u16*)p; p += (size_t)nb * SZ_TT;
  u16* Yt   = (u16*)p;

  transpose_cast2<<<dim3(32, 32, 2), dim3(32, 8), 0, stream>>>(Wq, WqT, Wk, WkT);
  cast_bf16<<<1024, 256, 0, stream>>>(Wv, Wvb);
  build_p<<<2048, 256, 0, stream>>>(v, P);
  // M = Wq^T * Wk  [V,V]
  gemm_bt<0, false><<<dim3(V_DIM / 256, V_DIM / 128, 1), 256, 0, stream>>>(
      WqT, V_DIM, 0, WkT, V_DIM, 0, Mb, V_DIM, 0, V_DIM, 0.f);

  for (int b0 = 0; b0 < B_DIM; b0 += nb) {
    gather_g<<<dim3(T_DIM, nb), 256, 0, stream>>>(idx, Mb, G, b0);
    gather_y<<<dim3(V_DIM, nb), 256, 0, stream>>>(idx, Wvb, Yt, b0);
    // A = tril(G * P^T): 72 tril 128x256 tiles, bn-desc heavy-first
    gemm_bt<1, false><<<dim3(nb, 72, 1), 256, 0, stream>>>(
        G, T_DIM, (long long)T_DIM * T_DIM, P, T_DIM, 0,
        Abuf, T_DIM, (long long)T_DIM * T_DIM, T_DIM, 0.f);
    // out = A * Yt^T + 0.001, kmax=(bm+1)*128, bm desc heavy-first
    gemm_bt<2, true><<<dim3(V_DIM / 256, nb, NT), 256, 0, stream>>>(
        Abuf, T_DIM, (long long)T_DIM * T_DIM, Yt, T_DIM, (long long)V_DIM * T_DIM,
        out + (long long)b0 * T_DIM * V_DIM, V_DIM, (long long)T_DIM * V_DIM,
        T_DIM, 0.001f);
  }
}

// Round 5
// 236.599 us; speedup vs baseline: 1.1423x; 1.1423x over previous
//
#include <hip/hip_runtime.h>
#include <stdint.h>

#define T_DIM 2048
#define V_DIM 1024
#define B_DIM 8
#define NT 16            // T_DIM/128

typedef unsigned int u32;
typedef unsigned short u16;
typedef unsigned char u8;
typedef __attribute__((ext_vector_type(8))) short s16x8;
typedef __attribute__((ext_vector_type(4))) float f32x4;

__device__ __forceinline__ u16 f2bf(float x) {
  u32 u = __builtin_bit_cast(u32, x);
  u = u + 0x7FFFu + ((u >> 16) & 1u);   // round-to-nearest-even
  return (u16)(u >> 16);
}

// async global->LDS, 16B per lane (m97 pattern)
#define GLD16(gp, lp) __builtin_amdgcn_global_load_lds( \
    (const __attribute__((address_space(1))) u32*)(gp), \
    (__attribute__((address_space(3))) u32*)(lp), 16, 0, 0)

// A-GEMM tile order, weight-descending; entry = (bm<<3)|bn, w=min(bm+1,2bn+2)
__device__ const u8 TRIL_ORD[72] = {
  127, 119,                                                        // 16,15
  126, 118, 110,  102,                                             // 14x3, 13
  125, 117, 109, 101, 93,  85,                                     // 12x5, 11
  124, 116, 108, 100, 92, 84, 76,  68,                             // 10x7, 9
  123, 115, 107, 99, 91, 83, 75, 67, 59,  51,                      // 8x9, 7
  122, 114, 106, 98, 90, 82, 74, 66, 58, 50, 42,  34,              // 6x11, 5
  121, 113, 105, 97, 89, 81, 73, 65, 57, 49, 41, 33, 25,  17,      // 4x13, 3
  120, 112, 104, 96, 88, 80, 72, 64, 56, 48, 40, 32, 24, 16, 8,  0 // 2x15, 1
};

// ---------------------------------------------------------------------------
// C[m,n] = sum_k A[m,k] * Bt[n,k]   (bf16 row-major, fp32 accum)
// 128x256 tile, BK=64, 256 threads = 4 waves (2x2), each wave 64m x 128n.
// LDS rows are 64 elems = 8 chunks of 16B; physical slot p of row r holds
// logical chunk (p - r) & 7  ->  fragment reads put exactly 8 lanes on each
// 4-bank group (2/bank = free).
// MODE 0: plain; grid (N/256, M/128, nz).
// MODE 1: tril(A) out, T x T. grid (576): job j = lam<256?lam : lam<512?
//         767-lam : lam  (complementary pairing); tau=j>>3 via TRIL_ORD,
//         bz=j&7. kmax=min((bm+1)*128,(bn+1)*256); epilogue masks gc>gr.
// MODE 2: causal-K, kmax=(bm+1)*128. grid (512): lam&255 -> (zq,n,bz);
//         bm = lam<256 ? 15-zq : zq  (pairs sum to 17 units per CU).
// F32OUT: write float + bias, else bf16.
// ---------------------------------------------------------------------------
template<int MODE, bool F32OUT>
__global__ void __launch_bounds__(256, 2)
gemm_bt(const u16* __restrict__ A, int lda, long long batchA,
        const u16* __restrict__ Bt, int ldb, long long batchB,
        void* __restrict__ Cv, int ldc, long long batchC,
        int K, float bias)
{
  int bn, bm, bz;
  if (MODE == 0) {
    bn = blockIdx.x; bm = blockIdx.y; bz = blockIdx.z;
  } else if (MODE == 1) {
    int lam = blockIdx.x;
    int j = (lam < 256) ? lam : (lam < 512 ? 767 - lam : lam);
    int tau = j >> 3; bz = j & 7;
    int pk = TRIL_ORD[tau]; bm = pk >> 3; bn = pk & 7;
  } else {                           // MODE 2
    int lam = blockIdx.x;
    int rr2 = lam & 255;
    int zq = rr2 >> 5;
    bn = (rr2 >> 3) & 3;
    bz = rr2 & 7;
    bm = (lam < 256) ? 15 - zq : zq;
  }
  const u16* Ab = A + (long long)bz * batchA;
  const u16* Bb = Bt + (long long)bz * batchB;
  int m0 = bm * 128, n0 = bn * 256;
  int kmax = K;
  if (MODE == 1) {
    int kl1 = (bm + 1) * 128, kl2 = (bn + 1) * 256;
    int kl = kl1 < kl2 ? kl1 : kl2;
    kmax = kl < K ? kl : K;
  }
  if (MODE == 2) { int kl = (bm + 1) * 128; kmax = kl < K ? kl : K; }

  __shared__ u16 As[128 * 64];   // 16 KB
  __shared__ u16 Bs[256 * 64];   // 32 KB

  int tid = threadIdx.x;
  int lane = tid & 63;
  int wid = tid >> 6;
  int wm = wid >> 1, wn = wid & 1;

  f32x4 acc[4][8] = {};

  // staging: pass i: row r = (tid>>3)+32i, slot p = tid&7 holds logical
  // chunk (p - r)&7; gcol constant across passes (32i == 0 mod 8).
  int r0 = tid >> 3;
  int gcol = (((tid & 7) - r0) & 7) * 8;
  const u16* ga = Ab + (long long)(m0 + r0) * lda + gcol;
  const u16* gb = Bb + (long long)(n0 + r0) * ldb + gcol;
  u16* la = As + tid * 8;        // byte offset tid*16 (wave-contiguous)
  u16* lb = Bs + tid * 8;
  long long lda32 = (long long)32 * lda;
  long long ldb32 = (long long)32 * ldb;

  int rm = lane & 15;
  int q = lane >> 4;

  for (int k0 = 0; k0 < kmax; k0 += 64) {
#pragma unroll
    for (int i = 0; i < 4; i++)
      GLD16(ga + k0 + i * lda32, la + i * 2048);
#pragma unroll
    for (int i = 0; i < 8; i++)
      GLD16(gb + k0 + i * ldb32, lb + i * 2048);
    __syncthreads();
#pragma unroll
    for (int ks = 0; ks < 2; ks++) {
      s16x8 af[4], bfv[8];
#pragma unroll
      for (int mi = 0; mi < 4; mi++) {
        int row = wm * 64 + mi * 16 + rm;
        int p = ((ks * 4 + q) + row) & 7;
        af[mi] = *(const s16x8*)&As[row * 64 + p * 8];
      }
#pragma unroll
      for (int ni = 0; ni < 8; ni++) {
        int row = wn * 128 + ni * 16 + rm;
        int p = ((ks * 4 + q) + row) & 7;
        bfv[ni] = *(const s16x8*)&Bs[row * 64 + p * 8];
      }
#pragma unroll
      for (int mi = 0; mi < 4; mi++)
#pragma unroll
        for (int ni = 0; ni < 8; ni++)
          acc[mi][ni] = __builtin_amdgcn_mfma_f32_16x16x32_bf16(
              af[mi], bfv[ni], acc[mi][ni], 0, 0, 0);
    }
    __syncthreads();
  }

  // C/D layout (m89-verified): col = lane&15, row = (lane>>4)*4 + reg
  int col = lane & 15;
  int rq = (lane >> 4) * 4;
#pragma unroll
  for (int mi = 0; mi < 4; mi++) {
#pragma unroll
    for (int ni = 0; ni < 8; ni++) {
      int lr = wm * 64 + mi * 16 + rq;          // local row (base of 4)
      int lc = wn * 128 + ni * 16 + col;        // local col
#pragma unroll
      for (int rr = 0; rr < 4; rr++) {
        float val = acc[mi][ni][rr];
        if (MODE == 1 && (n0 + lc) > (m0 + lr + rr)) val = 0.f;  // causal
        long long off = (long long)(m0 + lr + rr) * ldc + (n0 + lc);
        if (F32OUT) {
          float* C = (float*)Cv + (long long)bz * batchC;
          C[off] = val + bias;
        } else {
          u16* C = (u16*)Cv + (long long)bz * batchC;
          C[off] = f2bf(val);
        }
      }
    }
  }
}

// ---------------------------------------------------------------------------
// transpose + cast two VxV fp32 matrices -> bf16 (dst[i][o] = src[o][i])
// ---------------------------------------------------------------------------
__global__ void transpose_cast2(const float* __restrict__ s0, u16* __restrict__ d0,
                                const float* __restrict__ s1, u16* __restrict__ d1)
{
  const float* src = blockIdx.z ? s1 : s0;
  u16* dst = blockIdx.z ? d1 : d0;
  __shared__ float tile[32][33];
  int x0 = blockIdx.x * 32, y0 = blockIdx.y * 32;
  int tx = threadIdx.x, ty = threadIdx.y;
#pragma unroll
  for (int k = 0; k < 4; k++)
    tile[ty + k * 8][tx] = src[(long long)(y0 + ty + k * 8) * V_DIM + x0 + tx];
  __syncthreads();
#pragma unroll
  for (int k = 0; k < 4; k++)
    dst[(long long)(x0 + ty + k * 8) * V_DIM + y0 + tx] = f2bf(tile[tx][ty + k * 8]);
}

__global__ void cast_bf16(const float* __restrict__ src, u16* __restrict__ dst)
{
  int i = blockIdx.x * 1024 + threadIdx.x;
#pragma unroll
  for (int k = 0; k < 4; k++) dst[i + k * 256] = f2bf(src[i + k * 256]);
}

// P[s][u] = v[s-u] for u<=s else 0  (T x T bf16), 16B stores
__global__ void build_p(const float* __restrict__ v, u16* __restrict__ P)
{
  int gid = blockIdx.x * 256 + threadIdx.x;
  int e0 = gid * 8;
  int s = e0 >> 11, u0 = e0 & 2047;
  s16x8 o;
#pragma unroll
  for (int k = 0; k < 8; k++) {
    int u = u0 + k;
    o[k] = (short)((u <= s) ? f2bf(v[s - u]) : (u16)0);
  }
  *(s16x8*)&P[e0] = o;
}

// G[z][t][u] = M[idx[b,t]][idx[b,u]] — one block per (t,z), 16B stores
__global__ void __launch_bounds__(256)
gather_g(const int* __restrict__ idx, const u16* __restrict__ Mb,
         u16* __restrict__ G, int b0)
{
  int t = blockIdx.x, z = blockIdx.y;
  const int* idxrow = idx + (long long)(b0 + z) * T_DIM;
  __shared__ u16 Mrow[V_DIM];
  int tid = threadIdx.x;
  int rowid = idxrow[t];
  const u32* src = (const u32*)(Mb + (long long)rowid * V_DIM);
  u32* dstl = (u32*)Mrow;
  dstl[tid] = src[tid];
  dstl[tid + 256] = src[tid + 256];
  __syncthreads();
  int u0 = tid * 8;
  int4 i0 = *(const int4*)&idxrow[u0];
  int4 i1 = *(const int4*)&idxrow[u0 + 4];
  s16x8 o;
  o[0] = (short)Mrow[i0.x]; o[1] = (short)Mrow[i0.y];
  o[2] = (short)Mrow[i0.z]; o[3] = (short)Mrow[i0.w];
  o[4] = (short)Mrow[i1.x]; o[5] = (short)Mrow[i1.y];
  o[6] = (short)Mrow[i1.z]; o[7] = (short)Mrow[i1.w];
  *(s16x8*)&G[((long long)z * T_DIM + t) * T_DIM + u0] = o;
}

// Yt[z][j][s] = Wv[j][idx[b,s]] — one block per (j,z), 16B stores
__global__ void __launch_bounds__(256)
gather_y(const int* __restrict__ idx, const u16* __restrict__ Wvb,
         u16* __restrict__ Yt, int b0)
{
  int j = blockIdx.x, z = blockIdx.y;
  const int* idxrow = idx + (long long)(b0 + z) * T_DIM;
  __shared__ u16 Wrow[V_DIM];
  int tid = threadIdx.x;
  const u32* src = (const u32*)(Wvb + (long long)j * V_DIM);
  u32* dstl = (u32*)Wrow;
  dstl[tid] = src[tid];
  dstl[tid + 256] = src[tid + 256];
  __syncthreads();
  int s0 = tid * 8;
  int4 i0 = *(const int4*)&idxrow[s0];
  int4 i1 = *(const int4*)&idxrow[s0 + 4];
  s16x8 o;
  o[0] = (short)Wrow[i0.x]; o[1] = (short)Wrow[i0.y];
  o[2] = (short)Wrow[i0.z]; o[3] = (short)Wrow[i0.w];
  o[4] = (short)Wrow[i1.x]; o[5] = (short)Wrow[i1.y];
  o[6] = (short)Wrow[i1.z]; o[7] = (short)Wrow[i1.w];
  *(s16x8*)&Yt[((long long)z * V_DIM + j) * T_DIM + s0] = o;
}

// ---------------------------------------------------------------------------
extern "C" void kernel_launch(void* const* d_in, const int* in_sizes, int n_in,
                              void* d_out, int out_size, void* d_ws, size_t ws_size,
                              hipStream_t stream)
{
  const int*   idx = (const int*)d_in[0];
  const float* v   = (const float*)d_in[1];
  const float* Wk  = (const float*)d_in[2];
  const float* Wq  = (const float*)d_in[3];
  const float* Wv  = (const float*)d_in[4];
  float* out = (float*)d_out;

  char* p = (char*)d_ws;
  const size_t SZ_VV = (size_t)V_DIM * V_DIM * 2;   // 2 MB bf16
  const size_t SZ_TT = (size_t)T_DIM * T_DIM * 2;   // 8 MB bf16
  const size_t SZ_VT = (size_t)V_DIM * T_DIM * 2;   // 4 MB bf16
  u16* WqT = (u16*)p; p += SZ_VV;
  u16* WkT = (u16*)p; p += SZ_VV;
  u16* Wvb = (u16*)p; p += SZ_VV;
  u16* Mb  = (u16*)p; p += SZ_VV;
  u16* P   = (u16*)p; p += SZ_TT;
  size_t used = (size_t)(p - (char*)d_ws);
  size_t per = 2 * SZ_TT + SZ_VT;                    // G + A + Yt per batch
  int nb = 8;
  while (nb > 1 && used + (size_t)nb * per > ws_size) nb >>= 1;
  u16* G    = (u16*)p; p += (size_t)nb * SZ_TT;
  u16* Abuf = (u16*)p; p += (size_t)nb * SZ_TT;
  u16* Yt   = (u16*)p;

  transpose_cast2<<<dim3(32, 32, 2), dim3(32, 8), 0, stream>>>(Wq, WqT, Wk, WkT);
  cast_bf16<<<1024, 256, 0, stream>>>(Wv, Wvb);
  build_p<<<2048, 256, 0, stream>>>(v, P);
  // M = Wq^T * Wk  [V,V]
  gemm_bt<0, false><<<dim3(V_DIM / 256, V_DIM / 128, 1), 256, 0, stream>>>(
      WqT, V_DIM, 0, WkT, V_DIM, 0, Mb, V_DIM, 0, V_DIM, 0.f);

  for (int b0 = 0; b0 < B_DIM; b0 += nb) {
    gather_g<<<dim3(T_DIM, nb), 256, 0, stream>>>(idx, Mb, G, b0);
    gather_y<<<dim3(V_DIM, nb), 256, 0, stream>>>(idx, Wvb, Yt, b0);
    // A = tril(G * P^T): 72 tiles x nb batches, pairing-balanced (nb==8)
    gemm_bt<1, false><<<dim3(nb * 72, 1, 1), 256, 0, stream>>>(
        G, T_DIM, (long long)T_DIM * T_DIM, P, T_DIM, 0,
        Abuf, T_DIM, (long long)T_DIM * T_DIM, T_DIM, 0.f);
    // out = A * Yt^T + 0.001, causal-K, pairing-balanced (nb==8)
    gemm_bt<2, true><<<dim3((V_DIM / 256) * nb * NT, 1, 1), 256, 0, stream>>>(
        Abuf, T_DIM, (long long)T_DIM * T_DIM, Yt, T_DIM, (long long)V_DIM * T_DIM,
        out + (long long)b0 * T_DIM * V_DIM, V_DIM, (long long)T_DIM * V_DIM,
        T_DIM, 0.001f);
  }
}

// Round 6
// 205.433 us; speedup vs baseline: 1.3156x; 1.1517x over previous
//
#include <hip/hip_runtime.h>
#include <stdint.h>

#define T_DIM 2048
#define V_DIM 1024
#define B_DIM 8
#define NT 16            // T_DIM/128

typedef unsigned int u32;
typedef unsigned short u16;
typedef __attribute__((ext_vector_type(8))) short s16x8;
typedef __attribute__((ext_vector_type(4))) float f32x4;

__device__ __forceinline__ u16 f2bf(float x) {
  u32 u = __builtin_bit_cast(u32, x);
  u = u + 0x7FFFu + ((u >> 16) & 1u);   // round-to-nearest-even
  return (u16)(u >> 16);
}

// async global->LDS, 16B per lane (m97 pattern)
#define GLD16(gp, lp) __builtin_amdgcn_global_load_lds( \
    (const __attribute__((address_space(1))) u32*)(gp), \
    (__attribute__((address_space(3))) u32*)(lp), 16, 0, 0)

// ---------------------------------------------------------------------------
// C[m,n] = sum_k A[m,k] * Bt[n,k]   (bf16 row-major, fp32 accum)
// 128x128 tile, BK=64, 256 threads = 4 waves (2x2), each wave 64x64.
// LDS rows 64 elems = 8 chunks of 16B; physical slot p of row r holds logical
// chunk (p - r)&7 -> fragment ds_read_b128 puts 8 lanes on each 4-bank group
// (2/bank = free).  32 KB LDS -> 3+ blocks/CU for latency overlap.
// MODE 0: plain; grid (N/128, M/128, nz).
// MODE 1: tril(A) out, T x T. grid (1088): tau=lam>>3 (bn-DESC = LPT),
//         bz=lam&7; kmax=(bn+1)*128; epilogue masks gc>gr.
// MODE 2: causal-K, kmax=(bm+1)*128. grid (1024): bm=15-(lam>>6) (LPT),
//         n=(lam>>3)&7, bz=lam&7.
// F32OUT: write float + bias, else bf16.
// ---------------------------------------------------------------------------
template<int MODE, bool F32OUT>
__global__ void __launch_bounds__(256, 2)
gemm_bt(const u16* __restrict__ A, int lda, long long batchA,
        const u16* __restrict__ Bt, int ldb, long long batchB,
        void* __restrict__ Cv, int ldc, long long batchC,
        int K, float bias)
{
  int bn, bm, bz;
  if (MODE == 0) {
    bn = blockIdx.x; bm = blockIdx.y; bz = blockIdx.z;
  } else if (MODE == 1) {
    int lam = blockIdx.x;
    int tau = lam >> 3; bz = lam & 7;
    int b = NT - 1, off = 0;                  // bn descending (heavy first)
    while (tau >= off + (NT - b)) { off += NT - b; b--; }
    bn = b; bm = b + (tau - off);
  } else {                                    // MODE 2
    int lam = blockIdx.x;
    bm = (NT - 1) - (lam >> 6);               // heavy first (LPT)
    bn = (lam >> 3) & 7;
    bz = lam & 7;
  }
  const u16* Ab = A + (long long)bz * batchA;
  const u16* Bb = Bt + (long long)bz * batchB;
  int m0 = bm * 128, n0 = bn * 128;
  int kmax = K;
  if (MODE == 1) { int kl = (bn + 1) * 128; kmax = kl < K ? kl : K; }
  if (MODE == 2) { int kl = (bm + 1) * 128; kmax = kl < K ? kl : K; }

  __shared__ u16 As[128 * 64];   // 16 KB
  __shared__ u16 Bs[128 * 64];   // 16 KB

  int tid = threadIdx.x;
  int lane = tid & 63;
  int wid = tid >> 6;
  int wm = wid >> 1, wn = wid & 1;

  f32x4 acc[4][4] = {};

  // staging: pass i: row r=(tid>>3)+32i, slot p=tid&7 holds logical chunk
  // (p - r)&7; gcol constant across passes (32i == 0 mod 8).
  int r0 = tid >> 3;
  int gcol = (((tid & 7) - r0) & 7) * 8;
  const u16* ga = Ab + (long long)(m0 + r0) * lda + gcol;
  const u16* gb = Bb + (long long)(n0 + r0) * ldb + gcol;
  u16* la = As + tid * 8;        // byte offset tid*16 (wave-contiguous)
  u16* lb = Bs + tid * 8;
  long long lda32 = (long long)32 * lda;
  long long ldb32 = (long long)32 * ldb;

  int rm = lane & 15;
  int q = lane >> 4;

  for (int k0 = 0; k0 < kmax; k0 += 64) {
#pragma unroll
    for (int i = 0; i < 4; i++)
      GLD16(ga + k0 + i * lda32, la + i * 2048);
#pragma unroll
    for (int i = 0; i < 4; i++)
      GLD16(gb + k0 + i * ldb32, lb + i * 2048);
    __syncthreads();
#pragma unroll
    for (int ks = 0; ks < 2; ks++) {
      s16x8 af[4], bfv[4];
#pragma unroll
      for (int mi = 0; mi < 4; mi++) {
        int row = wm * 64 + mi * 16 + rm;
        int p = ((ks * 4 + q) + row) & 7;
        af[mi] = *(const s16x8*)&As[row * 64 + p * 8];
      }
#pragma unroll
      for (int ni = 0; ni < 4; ni++) {
        int row = wn * 64 + ni * 16 + rm;
        int p = ((ks * 4 + q) + row) & 7;
        bfv[ni] = *(const s16x8*)&Bs[row * 64 + p * 8];
      }
#pragma unroll
      for (int mi = 0; mi < 4; mi++)
#pragma unroll
        for (int ni = 0; ni < 4; ni++)
          acc[mi][ni] = __builtin_amdgcn_mfma_f32_16x16x32_bf16(
              af[mi], bfv[ni], acc[mi][ni], 0, 0, 0);
    }
    __syncthreads();
  }

  // C/D layout (m89-verified): col = lane&15, row = (lane>>4)*4 + reg
  int col = lane & 15;
  int rq = (lane >> 4) * 4;
#pragma unroll
  for (int mi = 0; mi < 4; mi++) {
#pragma unroll
    for (int ni = 0; ni < 4; ni++) {
      int lr = wm * 64 + mi * 16 + rq;          // local row (base of 4)
      int lc = wn * 64 + ni * 16 + col;         // local col
#pragma unroll
      for (int rr = 0; rr < 4; rr++) {
        float val = acc[mi][ni][rr];
        if (MODE == 1 && (n0 + lc) > (m0 + lr + rr)) val = 0.f;  // causal
        long long off = (long long)(m0 + lr + rr) * ldc + (n0 + lc);
        if (F32OUT) {
          float* C = (float*)Cv + (long long)bz * batchC;
          C[off] = val + bias;
        } else {
          u16* C = (u16*)Cv + (long long)bz * batchC;
          C[off] = f2bf(val);
        }
      }
    }
  }
}

// ---------------------------------------------------------------------------
// prep: z<2: transpose+cast VxV fp32 -> bf16 (dst[i][o]=src[o][i]);
//       z==2: straight cast of Wv (1024 elems per block-row pair)
// ---------------------------------------------------------------------------
__global__ void prep_weights(const float* __restrict__ Wq, u16* __restrict__ WqT,
                             const float* __restrict__ Wk, u16* __restrict__ WkT,
                             const float* __restrict__ Wv, u16* __restrict__ Wvb)
{
  int z = blockIdx.z;
  if (z == 2) {
    int bx = blockIdx.y * 32 + blockIdx.x;
    int i = bx * 1024 + threadIdx.y * 32 + threadIdx.x;
#pragma unroll
    for (int k = 0; k < 4; k++) Wvb[i + k * 256] = f2bf(Wv[i + k * 256]);
    return;
  }
  const float* src = z ? Wk : Wq;
  u16* dst = z ? WkT : WqT;
  __shared__ float tile[32][33];
  int x0 = blockIdx.x * 32, y0 = blockIdx.y * 32;
  int tx = threadIdx.x, ty = threadIdx.y;
#pragma unroll
  for (int k = 0; k < 4; k++)
    tile[ty + k * 8][tx] = src[(long long)(y0 + ty + k * 8) * V_DIM + x0 + tx];
  __syncthreads();
#pragma unroll
  for (int k = 0; k < 4; k++)
    dst[(long long)(x0 + ty + k * 8) * V_DIM + y0 + tx] = f2bf(tile[tx][ty + k * 8]);
}

// P[s][u] = v[s-u] for u<=s else 0  (T x T bf16), 16B stores
__global__ void build_p(const float* __restrict__ v, u16* __restrict__ P)
{
  int gid = blockIdx.x * 256 + threadIdx.x;
  int e0 = gid * 8;
  int s = e0 >> 11, u0 = e0 & 2047;
  s16x8 o;
#pragma unroll
  for (int k = 0; k < 8; k++) {
    int u = u0 + k;
    o[k] = (short)((u <= s) ? f2bf(v[s - u]) : (u16)0);
  }
  *(s16x8*)&P[e0] = o;
}

// merged gather: bx<T: G[z][t][u]=M[idx[t]][idx[u]]; else Yt[z][j][s]=Wv[j][idx[s]]
__global__ void __launch_bounds__(256)
gather_gy(const int* __restrict__ idx, const u16* __restrict__ Mb,
          const u16* __restrict__ Wvb, u16* __restrict__ G,
          u16* __restrict__ Yt, int b0)
{
  int bx = blockIdx.x, z = blockIdx.y;
  const int* idxrow = idx + (long long)(b0 + z) * T_DIM;
  __shared__ u16 Row[V_DIM];
  int tid = threadIdx.x;
  const u32* src;
  u16* dst;
  if (bx < T_DIM) {
    src = (const u32*)(Mb + (long long)idxrow[bx] * V_DIM);
    dst = G + ((long long)z * T_DIM + bx) * T_DIM;
  } else {
    src = (const u32*)(Wvb + (long long)(bx - T_DIM) * V_DIM);
    dst = Yt + ((long long)z * V_DIM + (bx - T_DIM)) * T_DIM;
  }
  u32* dstl = (u32*)Row;
  dstl[tid] = src[tid];
  dstl[tid + 256] = src[tid + 256];
  __syncthreads();
  int s0 = tid * 8;
  int4 i0 = *(const int4*)&idxrow[s0];
  int4 i1 = *(const int4*)&idxrow[s0 + 4];
  s16x8 o;
  o[0] = (short)Row[i0.x]; o[1] = (short)Row[i0.y];
  o[2] = (short)Row[i0.z]; o[3] = (short)Row[i0.w];
  o[4] = (short)Row[i1.x]; o[5] = (short)Row[i1.y];
  o[6] = (short)Row[i1.z]; o[7] = (short)Row[i1.w];
  *(s16x8*)&dst[s0] = o;
}

// ---------------------------------------------------------------------------
extern "C" void kernel_launch(void* const* d_in, const int* in_sizes, int n_in,
                              void* d_out, int out_size, void* d_ws, size_t ws_size,
                              hipStream_t stream)
{
  const int*   idx = (const int*)d_in[0];
  const float* v   = (const float*)d_in[1];
  const float* Wk  = (const float*)d_in[2];
  const float* Wq  = (const float*)d_in[3];
  const float* Wv  = (const float*)d_in[4];
  float* out = (float*)d_out;

  char* p = (char*)d_ws;
  const size_t SZ_VV = (size_t)V_DIM * V_DIM * 2;   // 2 MB bf16
  const size_t SZ_TT = (size_t)T_DIM * T_DIM * 2;   // 8 MB bf16
  const size_t SZ_VT = (size_t)V_DIM * T_DIM * 2;   // 4 MB bf16
  u16* WqT = (u16*)p; p += SZ_VV;
  u16* WkT = (u16*)p; p += SZ_VV;
  u16* Wvb = (u16*)p; p += SZ_VV;
  u16* Mb  = (u16*)p; p += SZ_VV;
  u16* P   = (u16*)p; p += SZ_TT;
  size_t used = (size_t)(p - (char*)d_ws);
  size_t per = 2 * SZ_TT + SZ_VT;                    // G + A + Yt per batch
  int nb = 8;
  while (nb > 1 && used + (size_t)nb * per > ws_size) nb >>= 1;
  u16* G    = (u16*)p; p += (size_t)nb * SZ_TT;
  u16* Abuf = (u16*)p; p += (size_t)nb * SZ_TT;
  u16* Yt   = (u16*)p;

  prep_weights<<<dim3(32, 32, 3), dim3(32, 8), 0, stream>>>(Wq, WqT, Wk, WkT, Wv, Wvb);
  build_p<<<2048, 256, 0, stream>>>(v, P);
  // M = Wq^T * Wk  [V,V]
  gemm_bt<0, false><<<dim3(V_DIM / 128, V_DIM / 128, 1), 256, 0, stream>>>(
      WqT, V_DIM, 0, WkT, V_DIM, 0, Mb, V_DIM, 0, V_DIM, 0.f);

  for (int b0 = 0; b0 < B_DIM; b0 += nb) {
    gather_gy<<<dim3(T_DIM + V_DIM, nb), 256, 0, stream>>>(idx, Mb, Wvb, G, Yt, b0);
    // A = tril(G * P^T): 136 tril tiles x nb, bn-desc LPT
    gemm_bt<1, false><<<dim3(nb * 136, 1, 1), 256, 0, stream>>>(
        G, T_DIM, (long long)T_DIM * T_DIM, P, T_DIM, 0,
        Abuf, T_DIM, (long long)T_DIM * T_DIM, T_DIM, 0.f);
    // out = A * Yt^T + 0.001, causal-K, bm-desc LPT
    gemm_bt<2, true><<<dim3((V_DIM / 128) * nb * NT, 1, 1), 256, 0, stream>>>(
        Abuf, T_DIM, (long long)T_DIM * T_DIM, Yt, T_DIM, (long long)V_DIM * T_DIM,
        out + (long long)b0 * T_DIM * V_DIM, V_DIM, (long long)T_DIM * V_DIM,
        T_DIM, 0.001f);
  }
}